// Round 1
// baseline (467.341 us; speedup 1.0000x reference)
//
#include <hip/hip_runtime.h>
#include <math.h>

// GreedyRouter: softmax gating + top-8 + renormalize + histogram.
// Insight: renormalized top-k softmax == softmax over only the top-k logits
// (full-row denominator cancels), so we never compute the full softmax.

constexpr int NEXP  = 256;   // experts
constexpr int TOPK  = 8;
constexpr int TPB   = 256;   // threads per block == tokens per block
constexpr int CHUNK = 32;    // columns staged per LDS pass
constexpr int LDS_STRIDE = CHUNK + 1;  // 33: bank = (tid+j)%32 -> 2-way, free

__global__ __launch_bounds__(TPB) void router_kernel(
    const float* __restrict__ logits,
    float* __restrict__ out_logits,
    float* __restrict__ out_w,
    float* __restrict__ out_id,
    float* __restrict__ counts)
{
    __shared__ float tile[TPB * LDS_STRIDE];   // 33792 B
    __shared__ int   hist[NEXP];               // 1024 B

    const int tid  = threadIdx.x;
    const int tok0 = blockIdx.x * TPB;

    hist[tid] = 0;

    // per-thread sorted top-8 (descending); strict '>' + ascending index scan
    // reproduces jax.lax.top_k tie-breaking (lower index ranks first).
    float v[TOPK];
    int   id[TOPK];
#pragma unroll
    for (int k = 0; k < TOPK; ++k) { v[k] = -INFINITY; id[k] = 0; }

    constexpr int CG = CHUNK / 4;                   // 8 float4 col-groups
    constexpr int F4_PER_THREAD = TPB * CG / TPB;   // 8

    for (int c0 = 0; c0 < NEXP; c0 += CHUNK) {
        __syncthreads();   // tile free to overwrite (and hist init on iter 0)
        // Stage [256 tokens x 32 cols] chunk; fuse the logits passthrough
        // store (data already in registers). Coalesced float4 both ways.
#pragma unroll
        for (int i = 0; i < F4_PER_THREAD; ++i) {
            int f  = tid + TPB * i;   // flat float4 index in chunk
            int r  = f / CG;          // token row 0..255
            int cg = f % CG;          // col group 0..7
            size_t gidx = (size_t)(tok0 + r) * NEXP + c0 + cg * 4;
            float4 x = *(const float4*)(logits + gidx);
            *(float4*)(out_logits + gidx) = x;
            float* t = &tile[r * LDS_STRIDE + cg * 4];  // scalar writes: stride
            t[0] = x.x; t[1] = x.y; t[2] = x.z; t[3] = x.w; // 33 isn't 16B-aligned
        }
        __syncthreads();
        // Consume: each thread scans its own token's 32 staged values.
#pragma unroll
        for (int j = 0; j < CHUNK; ++j) {
            float x  = tile[tid * LDS_STRIDE + j];
            int   xi = c0 + j;
            // branch-free bubble insert into sorted-8
#pragma unroll
            for (int k = 0; k < TOPK; ++k) {
                bool  gt = x > v[k];
                float tv = v[k];
                int   ti = id[k];
                v[k]  = gt ? x  : tv;
                id[k] = gt ? xi : ti;
                x     = gt ? tv : x;
                xi    = gt ? ti : xi;
            }
        }
    }

    // softmax over the selected 8 (== renormalized full-row softmax)
    float e[TOPK];
    float s = 0.f;
#pragma unroll
    for (int k = 0; k < TOPK; ++k) { e[k] = __expf(v[k] - v[0]); s += e[k]; }
    const float inv = 1.0f / s;

    const int token = tok0 + tid;
#pragma unroll
    for (int k = 0; k < TOPK; ++k) {
        out_w [(size_t)token * TOPK + k] = e[k] * inv;
        out_id[(size_t)token * TOPK + k] = (float)id[k];  // ids as f32 values
        atomicAdd(&hist[id[k]], 1);
    }
    __syncthreads();
    // one global atomic per (block, expert)
    atomicAdd(&counts[tid], (float)hist[tid]);
}

extern "C" void kernel_launch(void* const* d_in, const int* in_sizes, int n_in,
                              void* d_out, int out_size, void* d_ws, size_t ws_size,
                              hipStream_t stream) {
    const float* logits = (const float*)d_in[0];
    const int n_tokens  = in_sizes[0] / NEXP;

    float* out        = (float*)d_out;
    float* out_logits = out;
    float* out_w      = out_logits + (size_t)n_tokens * NEXP;
    float* out_id     = out_w      + (size_t)n_tokens * TOPK;
    float* counts     = out_id     + (size_t)n_tokens * TOPK;

    // d_out is re-poisoned to 0xAA before every launch; histogram needs zeros.
    hipMemsetAsync(counts, 0, NEXP * sizeof(float), stream);

    const int blocks = n_tokens / TPB;  // 262144/256 = 1024
    router_kernel<<<blocks, TPB, 0, stream>>>(logits, out_logits, out_w,
                                              out_id, counts);
}